// Round 1
// baseline (2930.346 us; speedup 1.0000x reference)
//
#include <hip/hip_runtime.h>
#include <math.h>

#define T_   64
#define B_   2048
#define OBS_ 48
#define H_   256
#define G_   1024
#define M1_  512
#define M2_  256
#define A_   12
#define BH_  (B_ * H_)

__device__ __forceinline__ float sigm(float x) {
    return 1.0f / (1.0f + __expf(-x));
}
__device__ __forceinline__ float tanh_fast(float x) {
    x = fminf(fmaxf(x, -15.0f), 15.0f);
    float e = __expf(2.0f * x);
    return (e - 1.0f) / (e + 1.0f);
}
__device__ __forceinline__ float elu(float x) {
    return x > 0.0f ? x : (__expf(x) - 1.0f);
}

// ---------------------------------------------------------------------------
// init: copy h0 -> H state buf 0, c0 -> C state buf (ws is poisoned each call)
// ---------------------------------------------------------------------------
__global__ void init_state(float* __restrict__ Hst, float* __restrict__ Cst,
                           const float* __restrict__ h0, const float* __restrict__ c0) {
    int i = blockIdx.x * 256 + threadIdx.x;
    Hst[i] = h0[i];
    Cst[i] = c0[i];
}

// ---------------------------------------------------------------------------
// LSTM step: g = [x_t | h*keep] @ [W_ih | W_hh]^T + b_ih + b_hh  (K = 48+256)
// Block: 256 threads = (16 j) x (16 b-groups); tile 64 b x 16 j x 4 gates.
// Epilogue fuses gate nonlinearities + c/h update.
// ---------------------------------------------------------------------------
__global__ __launch_bounds__(256) void lstm_step(
    const float* __restrict__ x_t,      // [B, 48]
    const int*   __restrict__ done_t,   // [B]
    const float* __restrict__ Hin,      // [B, H]
    float*       __restrict__ Hout,     // [B, H]
    float*       __restrict__ Cst,      // [B, H] in-place
    float*       __restrict__ hs_t,     // [B, H] or null
    const float* __restrict__ W_ih,     // [1024, 48]
    const float* __restrict__ W_hh,     // [1024, 256]
    const float* __restrict__ b_ih,     // [1024]
    const float* __restrict__ b_hh)     // [1024]
{
    __shared__ float a_sm[64][20];   // A tile: 64 b x 16 k (pad 20 -> 16B-aligned rows, low conflict)
    __shared__ float b_sm[64][20];   // B tile: 64 w-rows (4 gates x 16 j) x 16 k
    __shared__ float keep_sm[64];

    const int tid = threadIdx.x;
    const int tx = tid & 15;         // j within tile
    const int ty = tid >> 4;         // b group (4 rows each)
    const int b0 = blockIdx.x * 64;
    const int j0 = blockIdx.y * 16;

    if (tid < 64) keep_sm[tid] = 1.0f - (float)done_t[b0 + tid];

    float acc[4][4];                 // [gate][b-sub]
    #pragma unroll
    for (int g = 0; g < 4; ++g)
        #pragma unroll
        for (int r = 0; r < 4; ++r) acc[g][r] = 0.0f;

    const int srow  = tid >> 2;          // 0..63 staging row
    const int skoff = (tid & 3) * 4;     // 0,4,8,12
    const int gt_s = srow >> 4;
    const int jj_s = srow & 15;
    const int n_s  = gt_s * 256 + j0 + jj_s;   // W row index for staging

    for (int kt = 0; kt < 19; ++kt) {    // 304 = 19 * 16; tiles 0..2 are x, 3..18 are h
        const int k0 = kt * 16;
        __syncthreads();
        float4 av, bv;
        if (k0 < 48) {
            const int kg = k0 + skoff;
            av = *(const float4*)(x_t + (b0 + srow) * OBS_ + kg);
            bv = *(const float4*)(W_ih + n_s * OBS_ + kg);
        } else {
            const int kh = k0 - 48 + skoff;
            av = *(const float4*)(Hin + (b0 + srow) * H_ + kh);
            const float kp = keep_sm[srow];
            av.x *= kp; av.y *= kp; av.z *= kp; av.w *= kp;
            bv = *(const float4*)(W_hh + n_s * H_ + kh);
        }
        *(float4*)(&a_sm[srow][skoff]) = av;
        *(float4*)(&b_sm[srow][skoff]) = bv;
        __syncthreads();

        #pragma unroll
        for (int kk = 0; kk < 16; kk += 4) {
            float4 a[4];
            #pragma unroll
            for (int r = 0; r < 4; ++r)
                a[r] = *(const float4*)(&a_sm[ty * 4 + r][kk]);
            #pragma unroll
            for (int g = 0; g < 4; ++g) {
                float4 w = *(const float4*)(&b_sm[g * 16 + tx][kk]);
                #pragma unroll
                for (int r = 0; r < 4; ++r) {
                    acc[g][r] += a[r].x * w.x;
                    acc[g][r] += a[r].y * w.y;
                    acc[g][r] += a[r].z * w.z;
                    acc[g][r] += a[r].w * w.w;
                }
            }
        }
    }

    // epilogue: gates -> c,h
    const int j = j0 + tx;
    float bias[4];
    #pragma unroll
    for (int g = 0; g < 4; ++g)
        bias[g] = b_ih[g * 256 + j] + b_hh[g * 256 + j];

    #pragma unroll
    for (int r = 0; r < 4; ++r) {
        const int b = b0 + ty * 4 + r;
        const float i_ = acc[0][r] + bias[0];
        const float f_ = acc[1][r] + bias[1];
        const float g_ = acc[2][r] + bias[2];
        const float o_ = acc[3][r] + bias[3];
        const float cold = Cst[b * H_ + j] * keep_sm[ty * 4 + r];
        const float cn = sigm(f_) * cold + sigm(i_) * tanh_fast(g_);
        const float hn = sigm(o_) * tanh_fast(cn);
        Cst[b * H_ + j]  = cn;
        Hout[b * H_ + j] = hn;
        if (hs_t) hs_t[b * H_ + j] = hn;
    }
}

// ---------------------------------------------------------------------------
// Fused LN -> MLP(256->512->256, ELU) -> heads -> [mean(12), logp, ent]
// One block = 16 rows, 256 threads.
// ---------------------------------------------------------------------------
__global__ __launch_bounds__(256) void mlp_kernel(
    const float* __restrict__ hsrc,   // [nrows, 256]
    float*       __restrict__ outb,   // [nrows, 14]
    const float* __restrict__ lng, const float* __restrict__ lnb,
    const float* __restrict__ W1,  const float* __restrict__ b1,
    const float* __restrict__ W2,  const float* __restrict__ b2,
    const float* __restrict__ Wm,  const float* __restrict__ bm,
    const float* __restrict__ Ws,  const float* __restrict__ bs)
{
    __shared__ float y_sm[16][260];    // LN output, later y2
    __shared__ float y1_sm[16][516];   // layer-1 output, later logstd scratch

    const int tid  = threadIdx.x;
    const int row0 = blockIdx.x * 16;

    // ---- load 16 rows ----
    #pragma unroll
    for (int r = 0; r < 16; ++r)
        y_sm[r][tid] = hsrc[(size_t)(row0 + r) * H_ + tid];
    __syncthreads();

    // ---- LayerNorm: wave w handles rows 4w..4w+3 ----
    {
        const int wave = tid >> 6, lane = tid & 63;
        for (int rr = 0; rr < 4; ++rr) {
            const int r = wave * 4 + rr;
            float v[4]; float s = 0.0f, ss = 0.0f;
            #pragma unroll
            for (int jj = 0; jj < 4; ++jj) {
                v[jj] = y_sm[r][lane + 64 * jj];
                s += v[jj]; ss += v[jj] * v[jj];
            }
            #pragma unroll
            for (int off = 32; off > 0; off >>= 1) {
                s  += __shfl_down(s,  off);
                ss += __shfl_down(ss, off);
            }
            s  = __shfl(s, 0);
            ss = __shfl(ss, 0);
            const float mu   = s * (1.0f / 256.0f);
            const float var  = ss * (1.0f / 256.0f) - mu * mu;
            const float rstd = rsqrtf(var + 1e-5f);
            #pragma unroll
            for (int jj = 0; jj < 4; ++jj) {
                const int k = lane + 64 * jj;
                y_sm[r][k] = (v[jj] - mu) * rstd * lng[k] + lnb[k];
            }
        }
    }
    __syncthreads();

    // ---- Layer 1: y1 = ELU(y @ W1 + b1), thread -> columns {tid, tid+256} ----
    {
        float acc0[16], acc1[16];
        #pragma unroll
        for (int r = 0; r < 16; ++r) { acc0[r] = 0.0f; acc1[r] = 0.0f; }
        for (int k = 0; k < 256; k += 4) {
            const float wa0 = W1[(k + 0) * M1_ + tid];
            const float wa1 = W1[(k + 1) * M1_ + tid];
            const float wa2 = W1[(k + 2) * M1_ + tid];
            const float wa3 = W1[(k + 3) * M1_ + tid];
            const float wb0 = W1[(k + 0) * M1_ + tid + 256];
            const float wb1 = W1[(k + 1) * M1_ + tid + 256];
            const float wb2 = W1[(k + 2) * M1_ + tid + 256];
            const float wb3 = W1[(k + 3) * M1_ + tid + 256];
            #pragma unroll
            for (int r = 0; r < 16; ++r) {
                const float4 yv = *(const float4*)(&y_sm[r][k]);
                acc0[r] += yv.x * wa0; acc0[r] += yv.y * wa1;
                acc0[r] += yv.z * wa2; acc0[r] += yv.w * wa3;
                acc1[r] += yv.x * wb0; acc1[r] += yv.y * wb1;
                acc1[r] += yv.z * wb2; acc1[r] += yv.w * wb3;
            }
        }
        const float bA = b1[tid], bB = b1[tid + 256];
        #pragma unroll
        for (int r = 0; r < 16; ++r) {
            y1_sm[r][tid]       = elu(acc0[r] + bA);
            y1_sm[r][tid + 256] = elu(acc1[r] + bB);
        }
    }
    __syncthreads();

    // ---- Layer 2: y2 = ELU(y1 @ W2 + b2); halves of threads take 8 rows each ----
    {
        const int half = tid >> 7, mt = tid & 127, rb = half * 8;
        float c0a[8], c1a[8];
        #pragma unroll
        for (int r = 0; r < 8; ++r) { c0a[r] = 0.0f; c1a[r] = 0.0f; }
        for (int k = 0; k < 512; k += 4) {
            float wa[4], wb[4];
            #pragma unroll
            for (int kk = 0; kk < 4; ++kk) {
                wa[kk] = W2[(k + kk) * M2_ + mt];
                wb[kk] = W2[(k + kk) * M2_ + mt + 128];
            }
            #pragma unroll
            for (int r = 0; r < 8; ++r) {
                const float4 yv = *(const float4*)(&y1_sm[rb + r][k]);
                c0a[r] += yv.x * wa[0]; c0a[r] += yv.y * wa[1];
                c0a[r] += yv.z * wa[2]; c0a[r] += yv.w * wa[3];
                c1a[r] += yv.x * wb[0]; c1a[r] += yv.y * wb[1];
                c1a[r] += yv.z * wb[2]; c1a[r] += yv.w * wb[3];
            }
        }
        const float bA = b2[mt], bB = b2[mt + 128];
        #pragma unroll
        for (int r = 0; r < 8; ++r) {
            y_sm[rb + r][mt]       = elu(c0a[r] + bA);
            y_sm[rb + r][mt + 128] = elu(c1a[r] + bB);
        }
    }
    __syncthreads();

    // ---- Heads: mean + logstd dots; then logp/ent ----
    {
        float* ls = &y1_sm[0][0];   // scratch for clipped logstd [16][12]
        const int r = tid >> 4, q = tid & 15;
        if (q < 12) {
            float sm = 0.0f, sv = 0.0f;
            for (int k = 0; k < 256; k += 4) {
                const float4 yv = *(const float4*)(&y_sm[r][k]);
                sm += yv.x * Wm[(k + 0) * A_ + q]; sm += yv.y * Wm[(k + 1) * A_ + q];
                sm += yv.z * Wm[(k + 2) * A_ + q]; sm += yv.w * Wm[(k + 3) * A_ + q];
                sv += yv.x * Ws[(k + 0) * A_ + q]; sv += yv.y * Ws[(k + 1) * A_ + q];
                sv += yv.z * Ws[(k + 2) * A_ + q]; sv += yv.w * Ws[(k + 3) * A_ + q];
            }
            const float meanv = sm + bm[q];
            const float lstd  = fminf(fmaxf(sv + bs[q], -5.0f), 2.0f);
            outb[(size_t)(row0 + r) * 14 + q] = meanv;
            ls[r * 12 + q] = lstd;
        }
        __syncthreads();
        if (tid < 16) {
            float s = 0.0f;
            #pragma unroll
            for (int q2 = 0; q2 < 12; ++q2) s += ls[tid * 12 + q2];
            const float LOG2PI = 1.8378770664093453f;
            outb[(size_t)(row0 + tid) * 14 + 12] = -s - 12.0f * 0.5f * LOG2PI;
            outb[(size_t)(row0 + tid) * 14 + 13] =  s + 12.0f * (0.5f + 0.5f * LOG2PI);
        }
    }
}

// ---------------------------------------------------------------------------
extern "C" void kernel_launch(void* const* d_in, const int* in_sizes, int n_in,
                              void* d_out, int out_size, void* d_ws, size_t ws_size,
                              hipStream_t stream) {
    (void)in_sizes; (void)n_in; (void)out_size;
    const float* x    = (const float*)d_in[0];
    const int*   done = (const int*)  d_in[1];
    const float* h0   = (const float*)d_in[2];
    const float* c0   = (const float*)d_in[3];
    const float* W_ih = (const float*)d_in[4];
    const float* W_hh = (const float*)d_in[5];
    const float* b_ih = (const float*)d_in[6];
    const float* b_hh = (const float*)d_in[7];
    const float* lng  = (const float*)d_in[8];
    const float* lnb  = (const float*)d_in[9];
    const float* W1   = (const float*)d_in[10];
    const float* b1   = (const float*)d_in[11];
    const float* W2   = (const float*)d_in[12];
    const float* b2   = (const float*)d_in[13];
    const float* Wm   = (const float*)d_in[14];
    const float* bm   = (const float*)d_in[15];
    const float* Ws   = (const float*)d_in[16];
    const float* bs   = (const float*)d_in[17];
    float* out = (float*)d_out;

    float* Hb0 = (float*)d_ws;
    float* Hb1 = Hb0 + BH_;
    float* Cst = Hb1 + BH_;
    float* hs  = Cst + BH_;

    const size_t need_phase = (size_t)(3 * BH_ + (size_t)T_ * BH_) * sizeof(float);
    const bool phase = (ws_size >= need_phase);

    init_state<<<BH_ / 256, 256, 0, stream>>>(Hb0, Cst, h0, c0);

    for (int t = 0; t < T_; ++t) {
        const float* Hin  = (t & 1) ? Hb1 : Hb0;
        float*       Hout = (t & 1) ? Hb0 : Hb1;
        float*       hst  = phase ? (hs + (size_t)t * BH_) : nullptr;
        lstm_step<<<dim3(32, 16), 256, 0, stream>>>(
            x + (size_t)t * B_ * OBS_, done + (size_t)t * B_,
            Hin, Hout, Cst, hst, W_ih, W_hh, b_ih, b_hh);
        if (!phase) {
            mlp_kernel<<<B_ / 16, 256, 0, stream>>>(
                Hout, out + (size_t)t * B_ * 14,
                lng, lnb, W1, b1, W2, b2, Wm, bm, Ws, bs);
        }
    }
    if (phase) {
        mlp_kernel<<<(T_ * B_) / 16, 256, 0, stream>>>(
            hs, out, lng, lnb, W1, b1, W2, b2, Wm, bm, Ws, bs);
    }
}

// Round 2
// 1054.319 us; speedup vs baseline: 2.7794x; 2.7794x over previous
//
#include <hip/hip_runtime.h>
#include <hip/hip_bf16.h>
#include <math.h>

#define T_   64
#define B_   2048
#define OBS_ 48
#define H_   256
#define M1_  512
#define M2_  256
#define A_   12
#define BH_  (B_ * H_)
#define KP_  320   // padded K for scan: 64 (x, padded from 48) + 256 (h)

typedef unsigned short u16;
typedef __attribute__((ext_vector_type(8))) short bf16x8;
typedef __attribute__((ext_vector_type(4))) float f32x4;

static __device__ __forceinline__ u16 f2b(float f) {
    __hip_bfloat16 h = __float2bfloat16(f);
    return *reinterpret_cast<u16*>(&h);
}
static __device__ __forceinline__ float b2f(u16 u) {
    union { unsigned u32; float f; } v; v.u32 = ((unsigned)u) << 16; return v.f;
}
static __device__ __forceinline__ float sigm(float x) {
    return 1.0f / (1.0f + __expf(-x));
}
static __device__ __forceinline__ float tanh_fast(float x) {
    x = fminf(fmaxf(x, -15.0f), 15.0f);
    float e = __expf(2.0f * x);
    return (e - 1.0f) / (e + 1.0f);
}
static __device__ __forceinline__ float elu(float x) {
    return x > 0.0f ? x : (__expf(x) - 1.0f);
}

// ---------------------------------------------------------------------------
// Pre-pass kernels (all fully parallel, run once per launch)
// ---------------------------------------------------------------------------
__global__ void prep_xpad(const float* __restrict__ x, u16* __restrict__ xpad) {
    const int i = blockIdx.x * 256 + threadIdx.x;   // over T*B*64
    const int r = i >> 6, k = i & 63;
    xpad[i] = (k < OBS_) ? f2b(x[r * OBS_ + k]) : (u16)0;
}

__global__ void prep_wcat(const float* __restrict__ W_ih, const float* __restrict__ W_hh,
                          u16* __restrict__ Wcat) {
    const int n = blockIdx.x;        // 1024
    const int k = threadIdx.x;       // 320
    float v;
    if (k < OBS_)      v = W_ih[n * OBS_ + k];
    else if (k < 64)   v = 0.0f;
    else               v = W_hh[n * H_ + (k - 64)];
    Wcat[n * KP_ + k] = f2b(v);
}

__global__ void prep_w1t(const float* __restrict__ W1, u16* __restrict__ W1T) {
    // W1 [256][512] -> W1T [512][256]
    W1T[blockIdx.x * 256 + threadIdx.x] = f2b(W1[threadIdx.x * M1_ + blockIdx.x]);
}

__global__ void prep_w2t(const float* __restrict__ W2, u16* __restrict__ W2T) {
    // W2 [512][256] -> W2T [256][512]
    W2T[blockIdx.x * 512 + threadIdx.x] = f2b(W2[threadIdx.x * M2_ + blockIdx.x]);
}

__global__ void prep_wht(const float* __restrict__ Wm, const float* __restrict__ Ws,
                         u16* __restrict__ WhT) {
    // WhT [32][256]: rows 0..11 = Wm^T, 12..15 = 0, 16..27 = Ws^T, 28..31 = 0
    const int n = blockIdx.x, k = threadIdx.x;
    float v = 0.0f;
    if (n < 12)                 v = Wm[k * A_ + n];
    else if (n >= 16 && n < 28) v = Ws[k * A_ + (n - 16)];
    WhT[n * 256 + k] = f2b(v);
}

__global__ void init_state2(const float* __restrict__ h0, const float* __restrict__ c0,
                            u16* __restrict__ hs0, float* __restrict__ Cst) {
    const int i = blockIdx.x * 256 + threadIdx.x;
    hs0[i] = f2b(h0[i]);
    Cst[i] = c0[i];
}

// ---------------------------------------------------------------------------
// LSTM step via bf16 MFMA.
// Grid (32,16): block tile = 64 b-rows x (4 gates x 16 j) = 64x64 output.
// 4 waves of 32x32 (2x2 16x16x32 MFMA frags), K=320 in 10 k-steps.
// B-frags load directly from L2-resident Wcat; A staged through LDS with
// exact 0/1 keep-select. Gate fusion via LDS roundtrip of accumulators.
// ---------------------------------------------------------------------------
__global__ __launch_bounds__(256) void lstm_step_mfma(
    const u16*  __restrict__ xpad_t,  // [B][64]
    const int*  __restrict__ done_t,  // [B]
    const u16*  __restrict__ Hin,     // [B][256]
    u16*        __restrict__ Hout,    // [B][256]
    float*      __restrict__ Cst,     // [B][256]
    const u16*  __restrict__ Wcat,    // [1024][320]
    const float* __restrict__ b_ih,
    const float* __restrict__ b_hh)
{
    __shared__ u16   a_sm[64][56];    // 112B row stride: 16B-aligned, 2-way banks (free)
    __shared__ float g_sm[64][68];
    __shared__ float keep_sm[64];

    const int tid  = threadIdx.x;
    const int lane = tid & 63;
    const int wave = tid >> 6;
    const int wm = wave & 1, wn = wave >> 1;
    const int quad = lane >> 4, l16 = lane & 15;
    const int b0 = blockIdx.x * 64;
    const int j0 = blockIdx.y * 16;

    if (tid < 64) keep_sm[tid] = done_t[b0 + tid] ? 0.0f : 1.0f;
    __syncthreads();

    f32x4 acc00 = {0,0,0,0}, acc01 = {0,0,0,0}, acc10 = {0,0,0,0}, acc11 = {0,0,0,0};

    // B frag j of this wave covers gate (wn*2+j), col l16 -> W row gate*256 + j0 + l16
    const u16* wp0 = Wcat + ((size_t)((wn * 2 + 0) * 256 + j0 + l16)) * KP_ + quad * 8;
    const u16* wp1 = Wcat + ((size_t)((wn * 2 + 1) * 256 + j0 + l16)) * KP_ + quad * 8;

    const int srow = tid >> 2;
    const int soff = (tid & 3) * 8;

    for (int kt = 0; kt < 10; ++kt) {
        const int k0 = kt * 32;
        __syncthreads();
        uint4 av;
        if (k0 < 64) {
            av = *(const uint4*)(xpad_t + (size_t)(b0 + srow) * 64 + k0 + soff);
        } else {
            av = *(const uint4*)(Hin + (size_t)(b0 + srow) * H_ + (k0 - 64) + soff);
            if (keep_sm[srow] == 0.0f) av = make_uint4(0u, 0u, 0u, 0u);
        }
        *(uint4*)(&a_sm[srow][soff]) = av;
        __syncthreads();

        const bf16x8 af0 = *(const bf16x8*)(&a_sm[wm * 32 +  0 + l16][quad * 8]);
        const bf16x8 af1 = *(const bf16x8*)(&a_sm[wm * 32 + 16 + l16][quad * 8]);
        const bf16x8 bf0 = *(const bf16x8*)(wp0 + k0);
        const bf16x8 bf1 = *(const bf16x8*)(wp1 + k0);
        acc00 = __builtin_amdgcn_mfma_f32_16x16x32_bf16(af0, bf0, acc00, 0, 0, 0);
        acc01 = __builtin_amdgcn_mfma_f32_16x16x32_bf16(af0, bf1, acc01, 0, 0, 0);
        acc10 = __builtin_amdgcn_mfma_f32_16x16x32_bf16(af1, bf0, acc10, 0, 0, 0);
        acc11 = __builtin_amdgcn_mfma_f32_16x16x32_bf16(af1, bf1, acc11, 0, 0, 0);
    }

    // D layout: col = l16, row = quad*4 + reg
    #pragma unroll
    for (int r = 0; r < 4; ++r) {
        g_sm[wm * 32 +  0 + quad * 4 + r][wn * 32 +  0 + l16] = acc00[r];
        g_sm[wm * 32 +  0 + quad * 4 + r][wn * 32 + 16 + l16] = acc01[r];
        g_sm[wm * 32 + 16 + quad * 4 + r][wn * 32 +  0 + l16] = acc10[r];
        g_sm[wm * 32 + 16 + quad * 4 + r][wn * 32 + 16 + l16] = acc11[r];
    }
    __syncthreads();

    // epilogue: 4 b-rows per thread; gates i,f,g,o at g_sm cols g*16+jj
    const int jj = tid & 15;
    const int bq = tid >> 4;
    const int jg = j0 + jj;
    const float bi = b_ih[jg]       + b_hh[jg];
    const float bf = b_ih[256 + jg] + b_hh[256 + jg];
    const float bg = b_ih[512 + jg] + b_hh[512 + jg];
    const float bo = b_ih[768 + jg] + b_hh[768 + jg];
    #pragma unroll
    for (int r = 0; r < 4; ++r) {
        const int b = bq * 4 + r;
        const float gi = g_sm[b][jj]      + bi;
        const float gf = g_sm[b][16 + jj] + bf;
        const float gg = g_sm[b][32 + jj] + bg;
        const float go = g_sm[b][48 + jj] + bo;
        const size_t idx = (size_t)(b0 + b) * H_ + jg;
        const float cold = Cst[idx] * keep_sm[b];
        const float cn = sigm(gf) * cold + sigm(gi) * tanh_fast(gg);
        Cst[idx] = cn;
        Hout[idx] = f2b(sigm(go) * tanh_fast(cn));
    }
}

// ---------------------------------------------------------------------------
// Fused LN -> MLP -> heads, all GEMMs on MFMA. 32 rows per block, 4 waves.
// ---------------------------------------------------------------------------
__global__ __launch_bounds__(256) void mlp_mfma(
    const u16*  __restrict__ hs,    // [nrows][256] bf16
    float*      __restrict__ out,   // [nrows][14]
    const float* __restrict__ lng, const float* __restrict__ lnb,
    const u16*  __restrict__ W1T, const float* __restrict__ b1,
    const u16*  __restrict__ W2T, const float* __restrict__ b2,
    const u16*  __restrict__ WhT,
    const float* __restrict__ bm, const float* __restrict__ bs)
{
    __shared__ u16   ybf[32][264];   // LN output, later y2 (528B stride: aligned, 2-way banks)
    __shared__ u16   y1bf[32][520];
    __shared__ float ls[32][12];

    const int tid  = threadIdx.x;
    const int lane = tid & 63;
    const int wave = tid >> 6;
    const int quad = lane >> 4, l16 = lane & 15;
    const int row0 = blockIdx.x * 32;

    // ---- LayerNorm: 8 rows per wave, lane holds 4 cols ----
    {
        const float4 gv = *(const float4*)(lng + lane * 4);
        const float4 bv = *(const float4*)(lnb + lane * 4);
        for (int rr = 0; rr < 8; ++rr) {
            const int r = wave * 8 + rr;
            const ushort4 hv = *(const ushort4*)(hs + (size_t)(row0 + r) * H_ + lane * 4);
            const float v0 = b2f(hv.x), v1 = b2f(hv.y), v2 = b2f(hv.z), v3 = b2f(hv.w);
            float s  = v0 + v1 + v2 + v3;
            float ss = v0 * v0 + v1 * v1 + v2 * v2 + v3 * v3;
            #pragma unroll
            for (int off = 32; off > 0; off >>= 1) {
                s  += __shfl_down(s,  off);
                ss += __shfl_down(ss, off);
            }
            s = __shfl(s, 0); ss = __shfl(ss, 0);
            const float mu   = s * (1.0f / 256.0f);
            const float rstd = rsqrtf(ss * (1.0f / 256.0f) - mu * mu + 1e-5f);
            ushort4 o;
            o.x = f2b((v0 - mu) * rstd * gv.x + bv.x);
            o.y = f2b((v1 - mu) * rstd * gv.y + bv.y);
            o.z = f2b((v2 - mu) * rstd * gv.z + bv.z);
            o.w = f2b((v3 - mu) * rstd * gv.w + bv.w);
            *(ushort4*)(&ybf[r][lane * 4]) = o;
        }
    }
    __syncthreads();

    // ---- Layer 1: [32x256] @ W1T[512][256]^T -> y1 [32x512]; wave -> 128 cols ----
    {
        f32x4 acc[2][8];
        #pragma unroll
        for (int i = 0; i < 2; ++i)
            #pragma unroll
            for (int j = 0; j < 8; ++j) acc[i][j] = (f32x4){0,0,0,0};
        for (int kt = 0; kt < 8; ++kt) {
            const int k0 = kt * 32;
            const bf16x8 af0 = *(const bf16x8*)(&ybf[l16][k0 + quad * 8]);
            const bf16x8 af1 = *(const bf16x8*)(&ybf[16 + l16][k0 + quad * 8]);
            const u16* wp = W1T + (size_t)(wave * 128 + l16) * 256 + k0 + quad * 8;
            #pragma unroll
            for (int j = 0; j < 8; ++j) {
                const bf16x8 bw = *(const bf16x8*)(wp + (size_t)j * 16 * 256);
                acc[0][j] = __builtin_amdgcn_mfma_f32_16x16x32_bf16(af0, bw, acc[0][j], 0, 0, 0);
                acc[1][j] = __builtin_amdgcn_mfma_f32_16x16x32_bf16(af1, bw, acc[1][j], 0, 0, 0);
            }
        }
        #pragma unroll
        for (int j = 0; j < 8; ++j) {
            const int n = wave * 128 + j * 16 + l16;
            const float bb = b1[n];
            #pragma unroll
            for (int i = 0; i < 2; ++i)
                #pragma unroll
                for (int r = 0; r < 4; ++r)
                    y1bf[i * 16 + quad * 4 + r][n] = f2b(elu(acc[i][j][r] + bb));
        }
    }
    __syncthreads();

    // ---- Layer 2: [32x512] @ W2T[256][512]^T -> y2 [32x256]; wave -> 64 cols ----
    {
        f32x4 acc[2][4];
        #pragma unroll
        for (int i = 0; i < 2; ++i)
            #pragma unroll
            for (int j = 0; j < 4; ++j) acc[i][j] = (f32x4){0,0,0,0};
        for (int kt = 0; kt < 16; ++kt) {
            const int k0 = kt * 32;
            const bf16x8 af0 = *(const bf16x8*)(&y1bf[l16][k0 + quad * 8]);
            const bf16x8 af1 = *(const bf16x8*)(&y1bf[16 + l16][k0 + quad * 8]);
            const u16* wp = W2T + (size_t)(wave * 64 + l16) * 512 + k0 + quad * 8;
            #pragma unroll
            for (int j = 0; j < 4; ++j) {
                const bf16x8 bw = *(const bf16x8*)(wp + (size_t)j * 16 * 512);
                acc[0][j] = __builtin_amdgcn_mfma_f32_16x16x32_bf16(af0, bw, acc[0][j], 0, 0, 0);
                acc[1][j] = __builtin_amdgcn_mfma_f32_16x16x32_bf16(af1, bw, acc[1][j], 0, 0, 0);
            }
        }
        // ybf reads all completed before the post-L1 barrier; safe to overwrite
        #pragma unroll
        for (int j = 0; j < 4; ++j) {
            const int n = wave * 64 + j * 16 + l16;
            const float bb = b2[n];
            #pragma unroll
            for (int i = 0; i < 2; ++i)
                #pragma unroll
                for (int r = 0; r < 4; ++r)
                    ybf[i * 16 + quad * 4 + r][n] = f2b(elu(acc[i][j][r] + bb));
        }
    }
    __syncthreads();

    // ---- Heads: wave0 -> mean (WhT rows 0..15), wave1 -> logstd (rows 16..31) ----
    if (wave < 2) {
        f32x4 a0 = {0,0,0,0}, a1 = {0,0,0,0};
        const u16* wp = WhT + (size_t)(wave * 16 + l16) * 256 + quad * 8;
        for (int kt = 0; kt < 8; ++kt) {
            const int k0 = kt * 32;
            const bf16x8 af0 = *(const bf16x8*)(&ybf[l16][k0 + quad * 8]);
            const bf16x8 af1 = *(const bf16x8*)(&ybf[16 + l16][k0 + quad * 8]);
            const bf16x8 bw  = *(const bf16x8*)(wp + k0);
            a0 = __builtin_amdgcn_mfma_f32_16x16x32_bf16(af0, bw, a0, 0, 0, 0);
            a1 = __builtin_amdgcn_mfma_f32_16x16x32_bf16(af1, bw, a1, 0, 0, 0);
        }
        if (l16 < 12) {
            f32x4 aa[2] = {a0, a1};
            if (wave == 0) {
                const float bb = bm[l16];
                #pragma unroll
                for (int i = 0; i < 2; ++i)
                    #pragma unroll
                    for (int r = 0; r < 4; ++r) {
                        const int m = i * 16 + quad * 4 + r;
                        out[(size_t)(row0 + m) * 14 + l16] = aa[i][r] + bb;
                    }
            } else {
                const float bb = bs[l16];
                #pragma unroll
                for (int i = 0; i < 2; ++i)
                    #pragma unroll
                    for (int r = 0; r < 4; ++r) {
                        const int m = i * 16 + quad * 4 + r;
                        ls[m][l16] = fminf(fmaxf(aa[i][r] + bb, -5.0f), 2.0f);
                    }
            }
        }
    }
    __syncthreads();
    if (tid < 32) {
        float s = 0.0f;
        #pragma unroll
        for (int q = 0; q < 12; ++q) s += ls[tid][q];
        const float LOG2PI = 1.8378770664093453f;
        out[(size_t)(row0 + tid) * 14 + 12] = -s - 6.0f * LOG2PI;
        out[(size_t)(row0 + tid) * 14 + 13] =  s + 6.0f + 6.0f * LOG2PI;
    }
}

// ---------------------------------------------------------------------------
extern "C" void kernel_launch(void* const* d_in, const int* in_sizes, int n_in,
                              void* d_out, int out_size, void* d_ws, size_t ws_size,
                              hipStream_t stream) {
    (void)in_sizes; (void)n_in; (void)out_size; (void)ws_size;
    const float* x    = (const float*)d_in[0];
    const int*   done = (const int*)  d_in[1];
    const float* h0   = (const float*)d_in[2];
    const float* c0   = (const float*)d_in[3];
    const float* W_ih = (const float*)d_in[4];
    const float* W_hh = (const float*)d_in[5];
    const float* b_ih = (const float*)d_in[6];
    const float* b_hh = (const float*)d_in[7];
    const float* lng  = (const float*)d_in[8];
    const float* lnb  = (const float*)d_in[9];
    const float* W1   = (const float*)d_in[10];
    const float* b1   = (const float*)d_in[11];
    const float* W2   = (const float*)d_in[12];
    const float* b2   = (const float*)d_in[13];
    const float* Wm   = (const float*)d_in[14];
    const float* bm   = (const float*)d_in[15];
    const float* Ws   = (const float*)d_in[16];
    const float* bs   = (const float*)d_in[17];
    float* out = (float*)d_out;

    // workspace carve (~88 MB, ws_size >= 135 MB confirmed in round 1)
    unsigned char* p = (unsigned char*)d_ws;
    float* Cst = (float*)p;            p += (size_t)BH_ * 4;
    u16* hs    = (u16*)p;              p += (size_t)(T_ + 1) * BH_ * 2;
    u16* xpad  = (u16*)p;              p += (size_t)T_ * B_ * 64 * 2;
    u16* Wcat  = (u16*)p;              p += (size_t)1024 * KP_ * 2;
    u16* W1T   = (u16*)p;              p += (size_t)M1_ * H_ * 2;
    u16* W2T   = (u16*)p;              p += (size_t)M2_ * M1_ * 2;
    u16* WhT   = (u16*)p;              p += (size_t)32 * H_ * 2;

    prep_xpad<<<(T_ * B_ * 64) / 256, 256, 0, stream>>>(x, xpad);
    prep_wcat<<<1024, KP_, 0, stream>>>(W_ih, W_hh, Wcat);
    prep_w1t<<<M1_, 256, 0, stream>>>(W1, W1T);
    prep_w2t<<<M2_, 512, 0, stream>>>(W2, W2T);
    prep_wht<<<32, 256, 0, stream>>>(Wm, Ws, WhT);
    init_state2<<<BH_ / 256, 256, 0, stream>>>(h0, c0, hs, Cst);

    for (int t = 0; t < T_; ++t) {
        lstm_step_mfma<<<dim3(32, 16), 256, 0, stream>>>(
            xpad + (size_t)t * B_ * 64,
            done + (size_t)t * B_,
            hs + (size_t)t * BH_,
            hs + (size_t)(t + 1) * BH_,
            Cst, Wcat, b_ih, b_hh);
    }

    mlp_mfma<<<(T_ * B_) / 32, 256, 0, stream>>>(
        hs + BH_, out, lng, lnb, W1T, b1, W2T, b2, WhT, bm, bs);
}